// Round 5
// baseline (655.429 us; speedup 1.0000x reference)
//
#include <hip/hip_runtime.h>

#define HW   256
#define HW2  (HW * HW)
#define CIN  64
#define COUT 64

#define RXN  7            // staged rows: padded row coords c0-2 .. c0+4
#define CYN  70           // staged cols: padded col coords r0-2 .. r0+67
#define PSTR 491          // plane stride in words (7*70=490, +1 pad -> a-groups 8 banks apart)

typedef __attribute__((ext_vector_type(8))) short short8v;   // 8 bf16 = 4 VGPR
typedef __attribute__((ext_vector_type(4))) float f32x4;

__device__ __forceinline__ unsigned short f2bf(float f) {    // RNE fp32->bf16
  unsigned u = __float_as_uint(f);
  u = u + 0x7FFFu + ((u >> 16) & 1u);
  return (unsigned short)(u >> 16);
}

// ---------------------------------------------------------------------------
// Kernel W: pre-swizzle conv weights into MFMA A-fragment order (bf16).
// (verified R2; unchanged)
// ---------------------------------------------------------------------------
__global__ void wfrag_kernel(const float* __restrict__ w, short* __restrict__ wf) {
  const int T = blockIdx.x * 256 + threadIdx.x;      // 4608 fragments
  if (T >= 4608) return;
  const int l   = T & 63;
  const int t   = (T >> 6) & 3;
  const int g   = T >> 8;                            // icb*9 + n
  const int n   = g % 9;
  const int icb = g / 9;
  const int oc  = t * 16 + (l & 15);
  const int ic0 = icb * 32 + (l >> 4) * 8;
  short8v v;
#pragma unroll
  for (int e = 0; e < 8; ++e)
    v[e] = (short)f2bf(w[(oc * CIN + ic0 + e) * 9 + n]);
  *(short8v*)(wf + (size_t)T * 8) = v;
}

// ---------------------------------------------------------------------------
// Kernel A: offset conv — R0-verified single-pass 18-acc compute (x read 1x),
// R3-verified store layout off[b][c][ch][r].
// ---------------------------------------------------------------------------
__global__ __launch_bounds__(256, 4) void offs_kernel(
    const float* __restrict__ x, const float* __restrict__ pw,
    const float* __restrict__ pb, float* __restrict__ off)
{
  const int b  = blockIdx.y;
  const int bx = blockIdx.x;
  const int r = (bx >> 2) * 4 + (threadIdx.x >> 6);
  const int c = (bx & 3) * 64 + (threadIdx.x & 63);

  float acc[18];
#pragma unroll
  for (int m = 0; m < 18; ++m) acc[m] = pb[m];

  const float* xb = x + (size_t)b * CIN * HW2;
  for (int ic = 0; ic < CIN; ++ic) {
    const float* xc = xb + ic * HW2;
    float v[9];
#pragma unroll
    for (int dr = 0; dr < 3; ++dr) {
      const int rr = r - 1 + dr;
#pragma unroll
      for (int dc = 0; dc < 3; ++dc) {
        const int cc = c - 1 + dc;
        const bool ok = (rr >= 0) & (rr < HW) & (cc >= 0) & (cc < HW);
        v[dr * 3 + dc] = ok ? xc[rr * HW + cc] : 0.f;
      }
    }
#pragma unroll
    for (int m = 0; m < 18; ++m) {
      const float* wp = pw + ((m * CIN) + ic) * 9;   // uniform -> s_load
      float a = acc[m];
#pragma unroll
      for (int k = 0; k < 9; ++k) a = fmaf(wp[k], v[k], a);
      acc[m] = a;
    }
  }
#pragma unroll
  for (int m = 0; m < 18; ++m)
    off[((size_t)(b * HW + c) * 18 + m) * HW + r] = acc[m];
}

// ---------------------------------------------------------------------------
// Kernel B: LDS-staged sampling -> direct-register B-frags -> MFMA.
// Block: 64 rows x 1 col, 4 waves. Per icb-half: stage 32 planes x 7x70
// padded-window (zeros in ring) into LDS with coalesced row loads (each line
// touched once), then thread (i=lane&15, a=lane>>4) of wave w samples pixel
// r0+16w+i, planes a*8+e, from LDS (2-way bank aliasing = free).
// Per-tap wave-uniform fallback to R3-verified global gather if any corner
// falls outside the staged window (offsets are data-dependent).
// A-frag / B-frag / K-order / C-store: byte-identical to R2-verified scheme.
// ---------------------------------------------------------------------------
__global__ __launch_bounds__(256) void deform_kernel(
    const float* __restrict__ x, const float* __restrict__ off,
    const short* __restrict__ wf, float* __restrict__ out)
{
  __shared__ float sx[32 * PSTR];                    // 62,848 B

  const int b   = blockIdx.y;
  const int bx  = blockIdx.x;                        // 4 r-tiles * 256 cols
  const int r0  = (bx & 3) * 64;
  const int c0  = bx >> 2;
  const int tid = threadIdx.x;
  const int lane = tid & 63;
  const int w    = tid >> 6;
  const int i    = lane & 15;
  const int a    = (lane >> 4) & 3;
  const int r    = r0 + w * 16 + i;                  // this thread's pixel row

  // ---- corner tables for pixel (r, c0): local window coords + weights ----
  unsigned qip[9][2];                                // packed (lx*70+ly), 4x16b
  float    qg[9][4];
  unsigned inwm = 0;                                 // per-tap in-window bits
  const float* obp = off + (size_t)(b * HW + c0) * 18 * HW;
#pragma unroll
  for (int n = 0; n < 9; ++n) {
    const float ox = obp[(size_t)n * HW + r];
    const float oy = obp[(size_t)(9 + n) * HW + r];
    const float px = (float)(c0 + (n % 3)) + ox;     // transposed base: row ~ c
    const float py = (float)(r + (n / 3)) + oy;      // col ~ r
    const float fx = floorf(px);
    const float fy = floorf(py);
    int ltx = (int)fx, lty = (int)fy;
    int rbx = ltx + 1, rby = lty + 1;
    ltx = min(max(ltx, 0), HW + 1); lty = min(max(lty, 0), HW + 1);
    rbx = min(max(rbx, 0), HW + 1); rby = min(max(rby, 0), HW + 1);
    const float pxc = fminf(fmaxf(px, 0.f), (float)(HW + 1));
    const float pyc = fminf(fmaxf(py, 0.f), (float)(HW + 1));
    const float wxl = 1.f + (float)ltx - pxc;
    const float wxr = 1.f - ((float)rbx - pxc);
    const float wyl = 1.f + (float)lty - pyc;
    const float wyr = 1.f - ((float)rby - pyc);
    const int   cx[4] = { ltx, rbx, ltx, rbx };
    const int   cy[4] = { lty, rby, rby, lty };
    const float cg[4] = { wxl * wyl, wxr * wyr, wxl * wyr, wxr * wyl };
    bool inw = true;
    unsigned wo[4];
#pragma unroll
    for (int k = 0; k < 4; ++k) {
      const int lx = cx[k] - c0 + 2;                 // window-local row
      const int ly = cy[k] - r0 + 2;                 // window-local col
      inw = inw && (lx >= 0) && (lx < RXN) && (ly >= 0) && (ly < CYN);
      const int lxc = min(max(lx, 0), RXN - 1);
      const int lyc = min(max(ly, 0), CYN - 1);
      wo[k]    = (unsigned)(lxc * CYN + lyc);
      qg[n][k] = cg[k];                              // ring handled by staged 0s
    }
    qip[n][0] = wo[0] | (wo[1] << 16);
    qip[n][1] = wo[2] | (wo[3] << 16);
    inwm |= (inw ? 1u : 0u) << n;
  }

  f32x4 acc[4];
#pragma unroll
  for (int t = 0; t < 4; ++t) acc[t] = (f32x4){0.f, 0.f, 0.f, 0.f};

  const float* xb = x + (size_t)b * CIN * HW2;

  for (int icb = 0; icb < 2; ++icb) {
    // ---------------- stage 32 planes of the padded window ----------------
    const float* xsrc = xb + (size_t)(icb * 32) * HW2;
    for (int R = w; R < 32 * RXN; R += 4) {          // one 70-word row per wave
      const int pl  = R / RXN;
      const int rxl = R - pl * RXN;
      const int rx  = c0 - 2 + rxl;                  // padded row coord
      const bool rok = (rx >= 1) & (rx <= HW);
      const float* srow = xsrc + (size_t)pl * HW2
                        + (size_t)min(max(rx - 1, 0), HW - 1) * HW;
#pragma unroll
      for (int base = 0; base < CYN; base += 64) {
        const int cyl = base + lane;
        if (cyl < CYN) {
          const int cyp = r0 - 2 + cyl;              // padded col coord
          const bool ok = rok & (cyp >= 1) & (cyp <= HW);
          const float v = ok ? srow[min(max(cyp - 1, 0), HW - 1)] : 0.f;
          sx[pl * PSTR + rxl * CYN + cyl] = v;
        }
      }
    }
    __syncthreads();

    // ---------------- sample (LDS fast path) + MFMA ----------------------
    const short* wfb0 = wf + ((size_t)(icb * 9) * 4 * 64 + lane) * 8;
    const float* sbase = sx + a * 8 * PSTR;
#pragma unroll
    for (int n = 0; n < 9; ++n) {
      short8v bfr;
      if (__all((inwm >> n) & 1)) {
        const unsigned p0 = qip[n][0], p1 = qip[n][1];
        const int o0 = (int)(p0 & 0xFFFFu);
        const int o1 = (int)(p0 >> 16);
        const int o2 = (int)(p1 & 0xFFFFu);
        const int o3 = (int)(p1 >> 16);
        const float g0 = qg[n][0], g1 = qg[n][1], g2 = qg[n][2], g3 = qg[n][3];
#pragma unroll
        for (int e = 0; e < 8; ++e) {
          const float* se = sbase + e * PSTR;        // imm-offset ds_reads
          float sv = g0 * se[o0];
          sv = fmaf(g1, se[o1], sv);
          sv = fmaf(g2, se[o2], sv);
          sv = fmaf(g3, se[o3], sv);
          bfr[e] = (short)f2bf(sv);
        }
      } else {
        // rare fallback: R3-verified global-gather path for this tap
        const float ox = obp[(size_t)n * HW + r];
        const float oy = obp[(size_t)(9 + n) * HW + r];
        const float px = (float)(c0 + (n % 3)) + ox;
        const float py = (float)(r + (n / 3)) + oy;
        const float fx = floorf(px);
        const float fy = floorf(py);
        int ltx = (int)fx, lty = (int)fy;
        int rbx = ltx + 1, rby = lty + 1;
        ltx = min(max(ltx, 0), HW + 1); lty = min(max(lty, 0), HW + 1);
        rbx = min(max(rbx, 0), HW + 1); rby = min(max(rby, 0), HW + 1);
        const float pxc = fminf(fmaxf(px, 0.f), (float)(HW + 1));
        const float pyc = fminf(fmaxf(py, 0.f), (float)(HW + 1));
        const float wxl = 1.f + (float)ltx - pxc;
        const float wxr = 1.f - ((float)rbx - pxc);
        const float wyl = 1.f + (float)lty - pyc;
        const float wyr = 1.f - ((float)rby - pyc);
        const int   cxs[4] = { ltx, rbx, ltx, rbx };
        const int   cys[4] = { lty, rby, rby, lty };
        const float cgs[4] = { wxl * wyl, wxr * wyr, wxl * wyr, wxr * wyl };
        int gi[4]; float gw[4];
#pragma unroll
        for (int k = 0; k < 4; ++k) {
          const bool ok = (cxs[k] >= 1) & (cxs[k] <= HW) & (cys[k] >= 1) & (cys[k] <= HW);
          gi[k] = ok ? ((cxs[k] - 1) * HW + (cys[k] - 1)) : 0;
          gw[k] = ok ? cgs[k] : 0.f;
        }
        const float* xpl = xb + (size_t)(icb * 32 + a * 8) * HW2;
#pragma unroll
        for (int e = 0; e < 8; ++e) {
          const float* xe = xpl + (size_t)e * HW2;
          float sv = gw[0] * xe[gi[0]];
          sv = fmaf(gw[1], xe[gi[1]], sv);
          sv = fmaf(gw[2], xe[gi[2]], sv);
          sv = fmaf(gw[3], xe[gi[3]], sv);
          bfr[e] = (short)f2bf(sv);
        }
      }
      const short* wfb = wfb0 + (size_t)n * 4 * 64 * 8;
#pragma unroll
      for (int t = 0; t < 4; ++t) {
        const short8v afr = *(const short8v*)(wfb + (size_t)t * 64 * 8);
        acc[t] = __builtin_amdgcn_mfma_f32_16x16x32_bf16(afr, bfr, acc[t], 0, 0, 0);
      }
    }
    __syncthreads();
  }

  // C/D store (R2-verified): col = i = pixel, row(oc) = t*16 + a*4 + j.
#pragma unroll
  for (int t = 0; t < 4; ++t)
#pragma unroll
    for (int j = 0; j < 4; ++j) {
      const int oc = t * 16 + a * 4 + j;
      out[((size_t)(b * COUT + oc)) * HW2 + (size_t)r * HW + c0] = acc[t][j];
    }
}

// ---------------------------------------------------------------------------
extern "C" void kernel_launch(void* const* d_in, const int* in_sizes, int n_in,
                              void* d_out, int out_size, void* d_ws, size_t ws_size,
                              hipStream_t stream) {
  const float* x  = (const float*)d_in[0];   // (2,64,256,256)
  const float* pw = (const float*)d_in[1];   // (18,64,3,3)
  const float* pb = (const float*)d_in[2];   // (18,)
  const float* w  = (const float*)d_in[3];   // (64,64,3,3)
  float* out = (float*)d_out;                // (2,64,256,256)

  float* off = (float*)d_ws;                                   // 9,437,184 B
  short* wfg = (short*)((char*)d_ws + (size_t)2 * 18 * HW2 * 4); // +73,728 B

  wfrag_kernel<<<18, 256, 0, stream>>>(w, wfg);
  dim3 gridA(256, 2);
  offs_kernel<<<gridA, 256, 0, stream>>>(x, pw, pb, off);
  dim3 gridB(1024, 2);
  deform_kernel<<<gridB, 256, 0, stream>>>(x, off, wfg, out);
}

// Round 6
// 278.469 us; speedup vs baseline: 2.3537x; 2.3537x over previous
//
#include <hip/hip_runtime.h>

#define HW   256
#define HW2  (HW * HW)
#define CIN  64
#define COUT 64

#define RXN   7           // staged rows: padded row coords c0-2 .. c0+4
#define CYN   70          // staged cols: padded col coords r0-2 .. r0+67
#define NSITE (RXN * CYN) // 490
#define SSTR  72          // bytes per site: 32 bf16 planes + 4 pad halves

typedef __attribute__((ext_vector_type(8))) short short8v;     // 8 bf16
typedef __attribute__((ext_vector_type(4))) float f32x4;
typedef __attribute__((ext_vector_type(4))) unsigned uint4v;

__device__ __forceinline__ unsigned short f2bf(float f) {      // RNE fp32->bf16
  unsigned u = __float_as_uint(f);
  u = u + 0x7FFFu + ((u >> 16) & 1u);
  return (unsigned short)(u >> 16);
}
__device__ __forceinline__ unsigned cvt_pk_bf16(float lo, float hi) {
  unsigned r;                                                  // r = {hi16: bf16(hi), lo16: bf16(lo)}
  asm("v_cvt_pk_bf16_f32 %0, %1, %2" : "=v"(r) : "v"(lo), "v"(hi));
  return r;
}

// ---------------------------------------------------------------------------
// Kernel W: pre-swizzle conv weights into MFMA A-fragment order (bf16).
// (verified R2; unchanged)
// ---------------------------------------------------------------------------
__global__ void wfrag_kernel(const float* __restrict__ w, short* __restrict__ wf) {
  const int T = blockIdx.x * 256 + threadIdx.x;      // 4608 fragments
  if (T >= 4608) return;
  const int l   = T & 63;
  const int t   = (T >> 6) & 3;
  const int g   = T >> 8;                            // icb*9 + n
  const int n   = g % 9;
  const int icb = g / 9;
  const int oc  = t * 16 + (l & 15);
  const int ic0 = icb * 32 + (l >> 4) * 8;
  short8v v;
#pragma unroll
  for (int e = 0; e < 8; ++e)
    v[e] = (short)f2bf(w[(oc * CIN + ic0 + e) * 9 + n]);
  *(short8v*)(wf + (size_t)T * 8) = v;
}

// ---------------------------------------------------------------------------
// Kernel A: offset conv — R2-verified 3-way m-split (occupancy), R4-verified
// transposed store off[b][c][ch][r].
// ---------------------------------------------------------------------------
__global__ __launch_bounds__(256) void offs_kernel(
    const float* __restrict__ x, const float* __restrict__ pw,
    const float* __restrict__ pb, float* __restrict__ off)
{
  const int b  = blockIdx.y;
  const int mb = blockIdx.z * 6;             // 0, 6, 12
  const int bx = blockIdx.x;
  const int r = (bx >> 2) * 4 + (threadIdx.x >> 6);
  const int c = (bx & 3) * 64 + (threadIdx.x & 63);

  float acc[6];
#pragma unroll
  for (int m = 0; m < 6; ++m) acc[m] = pb[mb + m];

  const float* xb = x + (size_t)b * CIN * HW2;
  for (int ic = 0; ic < CIN; ++ic) {
    const float* xc = xb + ic * HW2;
    float v[9];
#pragma unroll
    for (int dr = 0; dr < 3; ++dr) {
      const int rr = r - 1 + dr;
#pragma unroll
      for (int dc = 0; dc < 3; ++dc) {
        const int cc = c - 1 + dc;
        const bool ok = (rr >= 0) & (rr < HW) & (cc >= 0) & (cc < HW);
        v[dr * 3 + dc] = ok ? xc[rr * HW + cc] : 0.f;
      }
    }
#pragma unroll
    for (int m = 0; m < 6; ++m) {
      const float* wp = pw + (((mb + m) * CIN) + ic) * 9;   // uniform -> s_load
      float a = acc[m];
#pragma unroll
      for (int k = 0; k < 9; ++k) a = fmaf(wp[k], v[k], a);
      acc[m] = a;
    }
  }
#pragma unroll
  for (int m = 0; m < 6; ++m)
    off[((size_t)(b * HW + c) * 18 + (mb + m)) * HW + r] = acc[m];
}

// ---------------------------------------------------------------------------
// Kernel B: bf16 LDS window (plane-minor, 72B/site) -> b64 corner reads ->
// register B-frags -> MFMA.  Block: 64 rows x 1 col, 4 waves.
// Staging: per plane-pair, lanes sweep sites; pack 2 planes -> ds_write_b32
//   (18-word lane stride -> 2-way, free). Window ring holds zeros.
// Sampling: lane(i=lane&15, a=lane>>4) of wave w owns pixel r0+16w+i, octet a.
//   Per tap n, corner k: 2x ds_read_b64 fetch 8 bf16 planes (aggregate
//   bank-perfect), unpack->f32, 4-corner FMA, v_cvt_pk_bf16_f32 repack.
// Fallback (wave-uniform, ~never): R2/R4-verified global fp32 gather.
// A-frag / K-order / MFMA / C-store: byte-identical to R2-verified scheme.
// ---------------------------------------------------------------------------
__global__ __launch_bounds__(256) void deform_kernel(
    const float* __restrict__ x, const float* __restrict__ off,
    const short* __restrict__ wf, float* __restrict__ out)
{
  __shared__ __align__(16) char sxb[NSITE * SSTR];   // 35,280 B

  const int b   = blockIdx.y;
  const int bx  = blockIdx.x;                        // 4 r-tiles * 256 cols
  const int r0  = (bx & 3) * 64;
  const int c0  = bx >> 2;
  const int tid = threadIdx.x;
  const int lane = tid & 63;
  const int i    = lane & 15;
  const int a    = (lane >> 4) & 3;
  const int wv   = tid >> 6;
  const int r    = r0 + wv * 16 + i;                 // this thread's pixel row

  // ---- corner tables for pixel (r, c0): window-local sites + weights ----
  unsigned qip[9][2];                                // packed site idx (<490), 4x16b
  float    qg[9][4];
  unsigned inwm = 0;                                 // per-tap in-window bits
  const float* obp = off + (size_t)(b * HW + c0) * 18 * HW;
#pragma unroll
  for (int n = 0; n < 9; ++n) {
    const float ox = obp[(size_t)n * HW + r];
    const float oy = obp[(size_t)(9 + n) * HW + r];
    const float px = (float)(c0 + (n % 3)) + ox;     // transposed base: row ~ c
    const float py = (float)(r + (n / 3)) + oy;      // col ~ r
    const float fx = floorf(px);
    const float fy = floorf(py);
    int ltx = (int)fx, lty = (int)fy;
    int rbx = ltx + 1, rby = lty + 1;
    ltx = min(max(ltx, 0), HW + 1); lty = min(max(lty, 0), HW + 1);
    rbx = min(max(rbx, 0), HW + 1); rby = min(max(rby, 0), HW + 1);
    const float pxc = fminf(fmaxf(px, 0.f), (float)(HW + 1));
    const float pyc = fminf(fmaxf(py, 0.f), (float)(HW + 1));
    const float wxl = 1.f + (float)ltx - pxc;
    const float wxr = 1.f - ((float)rbx - pxc);
    const float wyl = 1.f + (float)lty - pyc;
    const float wyr = 1.f - ((float)rby - pyc);
    const int   cx[4] = { ltx, rbx, ltx, rbx };
    const int   cy[4] = { lty, rby, rby, lty };
    const float cg[4] = { wxl * wyl, wxr * wyr, wxl * wyr, wxr * wyl };
    bool inw = true;
    unsigned so[4];
#pragma unroll
    for (int k = 0; k < 4; ++k) {
      const int lx = cx[k] - c0 + 2;                 // window-local row
      const int ly = cy[k] - r0 + 2;                 // window-local col
      inw = inw && (lx >= 0) && (lx < RXN) && (ly >= 0) && (ly < CYN);
      const int lxc = min(max(lx, 0), RXN - 1);
      const int lyc = min(max(ly, 0), CYN - 1);
      so[k]    = (unsigned)(lxc * CYN + lyc);
      qg[n][k] = cg[k];                              // ring zeros handle pad
    }
    qip[n][0] = so[0] | (so[1] << 16);
    qip[n][1] = so[2] | (so[3] << 16);
    inwm |= (inw ? 1u : 0u) << n;
  }

  f32x4 acc[4];
#pragma unroll
  for (int t = 0; t < 4; ++t) acc[t] = (f32x4){0.f, 0.f, 0.f, 0.f};

  const float* xb = x + (size_t)b * CIN * HW2;

  for (int icb = 0; icb < 2; ++icb) {
    // ------------- stage: 32 planes -> bf16 plane-minor window -------------
    const float* xsrc = xb + (size_t)(icb * 32) * HW2;
    for (int pp = 0; pp < 16; ++pp) {                // plane pair (2pp, 2pp+1)
      const float* x0 = xsrc + (size_t)(2 * pp) * HW2;
      const float* x1 = x0 + HW2;
      for (int s = tid; s < NSITE; s += 256) {
        const int rxl = s / CYN;
        const int cyl = s - rxl * CYN;
        const int rx  = c0 - 2 + rxl;                // padded row coord
        const int cyp = r0 - 2 + cyl;                // padded col coord
        const bool ok = (rx >= 1) & (rx <= HW) & (cyp >= 1) & (cyp <= HW);
        const int  gi = (rx - 1) * HW + (cyp - 1);
        const float v0 = ok ? x0[max(gi, 0)] : 0.f;
        const float v1 = ok ? x1[max(gi, 0)] : 0.f;
        *(unsigned*)(sxb + s * SSTR + pp * 4) = cvt_pk_bf16(v0, v1);
      }
    }
    __syncthreads();

    // ------------- sample from LDS + MFMA ---------------------------------
    const char*  sb   = sxb + a * 16;                // octet base (bytes)
    const short* wfb0 = wf + ((size_t)(icb * 9) * 4 * 64 + lane) * 8;
#pragma unroll
    for (int n = 0; n < 9; ++n) {
      short8v bfr;
      if (__all((inwm >> n) & 1)) {
        const unsigned s0 = qip[n][0] & 0xFFFFu, s1 = qip[n][0] >> 16;
        const unsigned s2 = qip[n][1] & 0xFFFFu, s3 = qip[n][1] >> 16;
        const uint2 c0lo = *(const uint2*)(sb + s0 * SSTR);
        const uint2 c0hi = *(const uint2*)(sb + s0 * SSTR + 8);
        const uint2 c1lo = *(const uint2*)(sb + s1 * SSTR);
        const uint2 c1hi = *(const uint2*)(sb + s1 * SSTR + 8);
        const uint2 c2lo = *(const uint2*)(sb + s2 * SSTR);
        const uint2 c2hi = *(const uint2*)(sb + s2 * SSTR + 8);
        const uint2 c3lo = *(const uint2*)(sb + s3 * SSTR);
        const uint2 c3hi = *(const uint2*)(sb + s3 * SSTR + 8);
        const float g0 = qg[n][0], g1 = qg[n][1], g2 = qg[n][2], g3 = qg[n][3];
        const unsigned u0[4] = { c0lo.x, c0lo.y, c0hi.x, c0hi.y };
        const unsigned u1[4] = { c1lo.x, c1lo.y, c1hi.x, c1hi.y };
        const unsigned u2[4] = { c2lo.x, c2lo.y, c2hi.x, c2hi.y };
        const unsigned u3[4] = { c3lo.x, c3lo.y, c3hi.x, c3hi.y };
        uint4v bw;
#pragma unroll
        for (int m = 0; m < 4; ++m) {
          const float a0l = __uint_as_float(u0[m] << 16);
          const float a0h = __uint_as_float(u0[m] & 0xFFFF0000u);
          const float a1l = __uint_as_float(u1[m] << 16);
          const float a1h = __uint_as_float(u1[m] & 0xFFFF0000u);
          const float a2l = __uint_as_float(u2[m] << 16);
          const float a2h = __uint_as_float(u2[m] & 0xFFFF0000u);
          const float a3l = __uint_as_float(u3[m] << 16);
          const float a3h = __uint_as_float(u3[m] & 0xFFFF0000u);
          float sl = g0 * a0l;
          sl = fmaf(g1, a1l, sl); sl = fmaf(g2, a2l, sl); sl = fmaf(g3, a3l, sl);
          float sh = g0 * a0h;
          sh = fmaf(g1, a1h, sh); sh = fmaf(g2, a2h, sh); sh = fmaf(g3, a3h, sh);
          bw[m] = cvt_pk_bf16(sl, sh);
        }
        bfr = __builtin_bit_cast(short8v, bw);
      } else {
        // rare fallback: R2/R4-verified global fp32 gather for this tap
        const float ox = obp[(size_t)n * HW + r];
        const float oy = obp[(size_t)(9 + n) * HW + r];
        const float px = (float)(c0 + (n % 3)) + ox;
        const float py = (float)(r + (n / 3)) + oy;
        const float fx = floorf(px);
        const float fy = floorf(py);
        int ltx = (int)fx, lty = (int)fy;
        int rbx = ltx + 1, rby = lty + 1;
        ltx = min(max(ltx, 0), HW + 1); lty = min(max(lty, 0), HW + 1);
        rbx = min(max(rbx, 0), HW + 1); rby = min(max(rby, 0), HW + 1);
        const float pxc = fminf(fmaxf(px, 0.f), (float)(HW + 1));
        const float pyc = fminf(fmaxf(py, 0.f), (float)(HW + 1));
        const float wxl = 1.f + (float)ltx - pxc;
        const float wxr = 1.f - ((float)rbx - pxc);
        const float wyl = 1.f + (float)lty - pyc;
        const float wyr = 1.f - ((float)rby - pyc);
        const int   cxs[4] = { ltx, rbx, ltx, rbx };
        const int   cys[4] = { lty, rby, rby, lty };
        const float cgs[4] = { wxl * wyl, wxr * wyr, wxl * wyr, wxr * wyl };
        int gi2[4]; float gw[4];
#pragma unroll
        for (int k = 0; k < 4; ++k) {
          const bool ok = (cxs[k] >= 1) & (cxs[k] <= HW) & (cys[k] >= 1) & (cys[k] <= HW);
          gi2[k] = ok ? ((cxs[k] - 1) * HW + (cys[k] - 1)) : 0;
          gw[k]  = ok ? cgs[k] : 0.f;
        }
        const float* xpl = xb + (size_t)(icb * 32 + a * 8) * HW2;
#pragma unroll
        for (int e = 0; e < 8; ++e) {
          const float* xe = xpl + (size_t)e * HW2;
          float sv = gw[0] * xe[gi2[0]];
          sv = fmaf(gw[1], xe[gi2[1]], sv);
          sv = fmaf(gw[2], xe[gi2[2]], sv);
          sv = fmaf(gw[3], xe[gi2[3]], sv);
          bfr[e] = (short)f2bf(sv);
        }
      }
      const short* wfb = wfb0 + (size_t)n * 4 * 64 * 8;
#pragma unroll
      for (int t = 0; t < 4; ++t) {
        const short8v afr = *(const short8v*)(wfb + (size_t)t * 64 * 8);
        acc[t] = __builtin_amdgcn_mfma_f32_16x16x32_bf16(afr, bfr, acc[t], 0, 0, 0);
      }
    }
    __syncthreads();
  }

  // C/D store (R2-verified): col = i = pixel, row(oc) = t*16 + a*4 + j.
#pragma unroll
  for (int t = 0; t < 4; ++t)
#pragma unroll
    for (int j = 0; j < 4; ++j) {
      const int oc = t * 16 + a * 4 + j;
      out[((size_t)(b * COUT + oc)) * HW2 + (size_t)r * HW + c0] = acc[t][j];
    }
}

// ---------------------------------------------------------------------------
extern "C" void kernel_launch(void* const* d_in, const int* in_sizes, int n_in,
                              void* d_out, int out_size, void* d_ws, size_t ws_size,
                              hipStream_t stream) {
  const float* x  = (const float*)d_in[0];   // (2,64,256,256)
  const float* pw = (const float*)d_in[1];   // (18,64,3,3)
  const float* pb = (const float*)d_in[2];   // (18,)
  const float* w  = (const float*)d_in[3];   // (64,64,3,3)
  float* out = (float*)d_out;                // (2,64,256,256)

  float* off = (float*)d_ws;                                   // 9,437,184 B
  short* wfg = (short*)((char*)d_ws + (size_t)2 * 18 * HW2 * 4); // +73,728 B

  wfrag_kernel<<<18, 256, 0, stream>>>(w, wfg);
  dim3 gridA(256, 2, 3);
  offs_kernel<<<gridA, 256, 0, stream>>>(x, pw, pb, off);
  dim3 gridB(1024, 2);
  deform_kernel<<<gridB, 256, 0, stream>>>(x, off, wfg, out);
}

// Round 7
// 265.613 us; speedup vs baseline: 2.4676x; 1.0484x over previous
//
#include <hip/hip_runtime.h>

#define HW   256
#define HW2  (HW * HW)
#define CIN  64
#define COUT 64

#define RXN   7              // staged rows: padded row coords c0-2 .. c0+4
#define CYN   70             // staged cols: padded col coords r0-2 .. r0+67
#define NSITE (RXN * CYN)    // 490
#define WSTR  18             // f32 words per site: 16 planes + 2 pad (bank spread)

typedef __attribute__((ext_vector_type(8))) short short8v;     // 8 bf16
typedef __attribute__((ext_vector_type(4))) float f32x4;
typedef __attribute__((ext_vector_type(4))) unsigned uint4v;

__device__ __forceinline__ unsigned short f2bf(float f) {      // RNE fp32->bf16
  unsigned u = __float_as_uint(f);
  u = u + 0x7FFFu + ((u >> 16) & 1u);
  return (unsigned short)(u >> 16);
}
__device__ __forceinline__ unsigned cvt_pk_bf16(float lo, float hi) {
  unsigned r;                                        // {hi16: bf16(hi), lo16: bf16(lo)}
  asm("v_cvt_pk_bf16_f32 %0, %1, %2" : "=v"(r) : "v"(lo), "v"(hi));
  return r;
}

// ---------------------------------------------------------------------------
// Kernel W: weights in tap-pair MFMA A-fragment order.
// K-step = (round rho: 16 ics) x (pair j: taps 2j, 2j+1). Lane l: a=l>>4,
// half=a>>1 (tap within pair), oct=a&1 (ic octet). Tap 9 = zero pad.
// wf[T=((rho*5+j)*4+t)*64+l][e] = bf16(w[16t+(l&15)][16rho+8oct+e][2j+half])
// ---------------------------------------------------------------------------
__global__ void wfrag_kernel(const float* __restrict__ w, short* __restrict__ wf) {
  const int T = blockIdx.x * 256 + threadIdx.x;      // 5120 fragments
  if (T >= 5120) return;
  const int l    = T & 63;
  const int t    = (T >> 6) & 3;
  const int g    = T >> 8;                           // rho*5 + j
  const int j    = g % 5;
  const int rho  = g / 5;
  const int half = (l >> 5) & 1;
  const int oct  = (l >> 4) & 1;
  const int n    = 2 * j + half;
  const int oc   = t * 16 + (l & 15);
  const int ic0  = rho * 16 + oct * 8;
  short8v v;
#pragma unroll
  for (int e = 0; e < 8; ++e)
    v[e] = (n < 9) ? (short)f2bf(w[(oc * CIN + ic0 + e) * 9 + n]) : (short)0;
  *(short8v*)(wf + (size_t)T * 8) = v;
}

// ---------------------------------------------------------------------------
// Kernel A: offset conv (R6-verified, unchanged). Store off[b][c][ch][r].
// ---------------------------------------------------------------------------
__global__ __launch_bounds__(256) void offs_kernel(
    const float* __restrict__ x, const float* __restrict__ pw,
    const float* __restrict__ pb, float* __restrict__ off)
{
  const int b  = blockIdx.y;
  const int mb = blockIdx.z * 6;             // 0, 6, 12
  const int bx = blockIdx.x;
  const int r = (bx >> 2) * 4 + (threadIdx.x >> 6);
  const int c = (bx & 3) * 64 + (threadIdx.x & 63);

  float acc[6];
#pragma unroll
  for (int m = 0; m < 6; ++m) acc[m] = pb[mb + m];

  const float* xb = x + (size_t)b * CIN * HW2;
  for (int ic = 0; ic < CIN; ++ic) {
    const float* xc = xb + ic * HW2;
    float v[9];
#pragma unroll
    for (int dr = 0; dr < 3; ++dr) {
      const int rr = r - 1 + dr;
#pragma unroll
      for (int dc = 0; dc < 3; ++dc) {
        const int cc = c - 1 + dc;
        const bool ok = (rr >= 0) & (rr < HW) & (cc >= 0) & (cc < HW);
        v[dr * 3 + dc] = ok ? xc[rr * HW + cc] : 0.f;
      }
    }
#pragma unroll
    for (int m = 0; m < 6; ++m) {
      const float* wp = pw + (((mb + m) * CIN) + ic) * 9;   // uniform -> s_load
      float a = acc[m];
#pragma unroll
      for (int k = 0; k < 9; ++k) a = fmaf(wp[k], v[k], a);
      acc[m] = a;
    }
  }
#pragma unroll
  for (int m = 0; m < 6; ++m)
    off[((size_t)(b * HW + c) * 18 + (mb + m)) * HW + r] = acc[m];
}

// ---------------------------------------------------------------------------
// Kernel B: f32 LDS window (16 planes/round, 18-word sites) -> b64 corner
// reads -> f32 interp (no unpack) -> bf16 B-frags -> tap-pair MFMA.
// 4 rounds (rho) x 5 tap-pairs (j); thread (i=lane&15, a) = pixel r0+16wv+i,
// tap 2j+(a>>1), ic octet 16rho+8(a&1). Tap 9 handled by zero qg + zero wf.
// Corner math / fallback / C-store: verified R2/R6 code.
// ---------------------------------------------------------------------------
__global__ __launch_bounds__(256) void deform_kernel(
    const float* __restrict__ x, const float* __restrict__ off,
    const short* __restrict__ wf, float* __restrict__ out)
{
  __shared__ float sxw[NSITE * WSTR];                // 35,280 B

  const int b    = blockIdx.y;
  const int bx   = blockIdx.x;                       // 4 r-tiles * 256 cols
  const int r0   = (bx & 3) * 64;
  const int c0   = bx >> 2;
  const int tid  = threadIdx.x;
  const int lane = tid & 63;
  const int i    = lane & 15;
  const int a    = (lane >> 4) & 3;
  const int oct  = a & 1;
  const int half = a >> 1;
  const int wv   = tid >> 6;
  const int r    = r0 + wv * 16 + i;                 // this thread's pixel row

  // ---- corner tables for this thread's 5 taps: n = 2*t5 + half ----------
  unsigned qip[5][2];                                // packed site idx, 4x16b
  float    qg[5][4];
  unsigned inwm = 0;
  const float* obp = off + (size_t)(b * HW + c0) * 18 * HW;
#pragma unroll
  for (int t5 = 0; t5 < 5; ++t5) {
    const int  n9  = 2 * t5 + half;
    const bool pad = (n9 >= 9);
    const int  n   = pad ? 0 : n9;
    const float ox = obp[(size_t)n * HW + r];
    const float oy = obp[(size_t)(9 + n) * HW + r];
    const float px = (float)(c0 + (n % 3)) + ox;     // transposed base: row ~ c
    const float py = (float)(r + (n / 3)) + oy;      // col ~ r
    const float fx = floorf(px);
    const float fy = floorf(py);
    int ltx = (int)fx, lty = (int)fy;
    int rbx = ltx + 1, rby = lty + 1;
    ltx = min(max(ltx, 0), HW + 1); lty = min(max(lty, 0), HW + 1);
    rbx = min(max(rbx, 0), HW + 1); rby = min(max(rby, 0), HW + 1);
    const float pxc = fminf(fmaxf(px, 0.f), (float)(HW + 1));
    const float pyc = fminf(fmaxf(py, 0.f), (float)(HW + 1));
    const float wxl = 1.f + (float)ltx - pxc;
    const float wxr = 1.f - ((float)rbx - pxc);
    const float wyl = 1.f + (float)lty - pyc;
    const float wyr = 1.f - ((float)rby - pyc);
    const int   cx[4] = { ltx, rbx, ltx, rbx };
    const int   cy[4] = { lty, rby, rby, lty };
    const float cg[4] = { wxl * wyl, wxr * wyr, wxl * wyr, wxr * wyl };
    bool inw = true;
    unsigned so[4];
#pragma unroll
    for (int k = 0; k < 4; ++k) {
      const int lx = cx[k] - c0 + 2;                 // window-local row
      const int ly = cy[k] - r0 + 2;                 // window-local col
      inw = inw && (lx >= 0) && (lx < RXN) && (ly >= 0) && (ly < CYN);
      const int lxc = min(max(lx, 0), RXN - 1);
      const int lyc = min(max(ly, 0), CYN - 1);
      so[k]    = (unsigned)(lxc * CYN + lyc);
      qg[t5][k] = pad ? 0.f : cg[k];                 // ring zeros handle border
    }
    qip[t5][0] = so[0] | (so[1] << 16);
    qip[t5][1] = so[2] | (so[3] << 16);
    inwm |= ((inw || pad) ? 1u : 0u) << t5;
  }

  // ---- staging site descriptors (sites tid and tid+256), reused 4 rounds --
  const int s1 = tid, s2 = tid + 256;
  int gi1 = 0, gi2 = 0; bool ok1, ok2;
  {
    const int rxl = s1 / CYN, cyl = s1 - rxl * CYN;
    const int rx = c0 - 2 + rxl, cyp = r0 - 2 + cyl;
    ok1 = (rx >= 1) & (rx <= HW) & (cyp >= 1) & (cyp <= HW);
    if (ok1) gi1 = (rx - 1) * HW + (cyp - 1);
  }
  {
    const int rxl = s2 / CYN, cyl = s2 - rxl * CYN;
    const int rx = c0 - 2 + rxl, cyp = r0 - 2 + cyl;
    ok2 = (s2 < NSITE) & (rx >= 1) & (rx <= HW) & (cyp >= 1) & (cyp <= HW);
    if (ok2) gi2 = (rx - 1) * HW + (cyp - 1);
  }

  f32x4 acc[4];
#pragma unroll
  for (int t = 0; t < 4; ++t) acc[t] = (f32x4){0.f, 0.f, 0.f, 0.f};

  const float* xb = x + (size_t)b * CIN * HW2;

#pragma unroll 1
  for (int rho = 0; rho < 4; ++rho) {
    // ------------- stage 16 f32 planes into the window --------------------
    const float* xsrc = xb + (size_t)(rho * 16) * HW2;
#pragma unroll
    for (int pp = 0; pp < 8; ++pp) {
      const float* x0 = xsrc + (size_t)(2 * pp) * HW2;
      const float* x1 = x0 + HW2;
      float2 v;
      v.x = ok1 ? x0[gi1] : 0.f;
      v.y = ok1 ? x1[gi1] : 0.f;
      *(float2*)(sxw + s1 * WSTR + 2 * pp) = v;
      if (s2 < NSITE) {
        float2 u;
        u.x = ok2 ? x0[gi2] : 0.f;
        u.y = ok2 ? x1[gi2] : 0.f;
        *(float2*)(sxw + s2 * WSTR + 2 * pp) = u;
      }
    }
    __syncthreads();

    // ------------- sample + MFMA over 5 tap-pairs -------------------------
    const short* wfr = wf + ((size_t)(rho * 5 * 4) * 64 + lane) * 8;
    const float* sbo = sxw + oct * 8;
#pragma unroll
    for (int j = 0; j < 5; ++j) {
      short8v bfr;
      if (__all((inwm >> j) & 1)) {
        const unsigned sA = qip[j][0] & 0xFFFFu, sB = qip[j][0] >> 16;
        const unsigned sC = qip[j][1] & 0xFFFFu, sD = qip[j][1] >> 16;
        const float2* pA = (const float2*)(sbo + sA * WSTR);
        const float2* pB = (const float2*)(sbo + sB * WSTR);
        const float2* pC = (const float2*)(sbo + sC * WSTR);
        const float2* pD = (const float2*)(sbo + sD * WSTR);
        const float g0 = qg[j][0], g1 = qg[j][1], g2 = qg[j][2], g3 = qg[j][3];
        uint4v bw;
#pragma unroll
        for (int m = 0; m < 4; ++m) {
          const float2 A = pA[m], B = pB[m], C = pC[m], D = pD[m];
          float sl = g0 * A.x;
          sl = fmaf(g1, B.x, sl); sl = fmaf(g2, C.x, sl); sl = fmaf(g3, D.x, sl);
          float sh = g0 * A.y;
          sh = fmaf(g1, B.y, sh); sh = fmaf(g2, C.y, sh); sh = fmaf(g3, D.y, sh);
          bw[m] = cvt_pk_bf16(sl, sh);
        }
        bfr = __builtin_bit_cast(short8v, bw);
      } else {
        // rare fallback: verified global fp32 gather for this thread's tap
        const int  n9  = 2 * j + half;
        const bool pad = (n9 >= 9);
        const int  n   = pad ? 0 : n9;
        const float ox = obp[(size_t)n * HW + r];
        const float oy = obp[(size_t)(9 + n) * HW + r];
        const float px = (float)(c0 + (n % 3)) + ox;
        const float py = (float)(r + (n / 3)) + oy;
        const float fx = floorf(px);
        const float fy = floorf(py);
        int ltx = (int)fx, lty = (int)fy;
        int rbx = ltx + 1, rby = lty + 1;
        ltx = min(max(ltx, 0), HW + 1); lty = min(max(lty, 0), HW + 1);
        rbx = min(max(rbx, 0), HW + 1); rby = min(max(rby, 0), HW + 1);
        const float pxc = fminf(fmaxf(px, 0.f), (float)(HW + 1));
        const float pyc = fminf(fmaxf(py, 0.f), (float)(HW + 1));
        const float wxl = 1.f + (float)ltx - pxc;
        const float wxr = 1.f - ((float)rbx - pxc);
        const float wyl = 1.f + (float)lty - pyc;
        const float wyr = 1.f - ((float)rby - pyc);
        const int   cxs[4] = { ltx, rbx, ltx, rbx };
        const int   cys[4] = { lty, rby, rby, lty };
        const float cgs[4] = { wxl * wyl, wxr * wyr, wxl * wyr, wxr * wyl };
        int gi[4]; float gw[4];
#pragma unroll
        for (int k = 0; k < 4; ++k) {
          const bool ok = (cxs[k] >= 1) & (cxs[k] <= HW) & (cys[k] >= 1) & (cys[k] <= HW);
          gi[k] = ok ? ((cxs[k] - 1) * HW + (cys[k] - 1)) : 0;
          gw[k] = (ok && !pad) ? cgs[k] : 0.f;
        }
        const float* xpl = xb + (size_t)(rho * 16 + oct * 8) * HW2;
#pragma unroll
        for (int e = 0; e < 8; ++e) {
          const float* xe = xpl + (size_t)e * HW2;
          float sv = gw[0] * xe[gi[0]];
          sv = fmaf(gw[1], xe[gi[1]], sv);
          sv = fmaf(gw[2], xe[gi[2]], sv);
          sv = fmaf(gw[3], xe[gi[3]], sv);
          bfr[e] = (short)f2bf(sv);
        }
      }
#pragma unroll
      for (int t = 0; t < 4; ++t) {
        const short8v afr = *(const short8v*)(wfr + ((size_t)(j * 4 + t)) * 64 * 8);
        acc[t] = __builtin_amdgcn_mfma_f32_16x16x32_bf16(afr, bfr, acc[t], 0, 0, 0);
      }
    }
    __syncthreads();
  }

  // C/D store (R2-verified): col = i = pixel, row(oc) = t*16 + a*4 + j.
#pragma unroll
  for (int t = 0; t < 4; ++t)
#pragma unroll
    for (int jj = 0; jj < 4; ++jj) {
      const int oc = t * 16 + a * 4 + jj;
      out[((size_t)(b * COUT + oc)) * HW2 + (size_t)r * HW + c0] = acc[t][jj];
    }
}

// ---------------------------------------------------------------------------
extern "C" void kernel_launch(void* const* d_in, const int* in_sizes, int n_in,
                              void* d_out, int out_size, void* d_ws, size_t ws_size,
                              hipStream_t stream) {
  const float* x  = (const float*)d_in[0];   // (2,64,256,256)
  const float* pw = (const float*)d_in[1];   // (18,64,3,3)
  const float* pb = (const float*)d_in[2];   // (18,)
  const float* w  = (const float*)d_in[3];   // (64,64,3,3)
  float* out = (float*)d_out;                // (2,64,256,256)

  float* off = (float*)d_ws;                                     // 9,437,184 B
  short* wfg = (short*)((char*)d_ws + (size_t)2 * 18 * HW2 * 4); // +81,920 B

  wfrag_kernel<<<20, 256, 0, stream>>>(w, wfg);
  dim3 gridA(256, 2, 3);
  offs_kernel<<<gridA, 256, 0, stream>>>(x, pw, pb, off);
  dim3 gridB(1024, 2);
  deform_kernel<<<gridB, 256, 0, stream>>>(x, off, wfg, out);
}

// Round 8
// 258.391 us; speedup vs baseline: 2.5366x; 1.0280x over previous
//
#include <hip/hip_runtime.h>

#define HW   256
#define HW2  (HW * HW)
#define CIN  64
#define COUT 64

#define RXN   7              // staged rows: padded row coords c0-2 .. c0+4
#define CYN   70             // staged cols: padded col coords r0-2 .. r0+67
#define NSITE (RXN * CYN)    // 490
#define SSTR  48             // bytes/site: 16 bf16 planes (32B) + 16B pad; 16-aligned

typedef __attribute__((ext_vector_type(8))) short short8v;     // 8 bf16
typedef __attribute__((ext_vector_type(4))) float f32x4;
typedef __attribute__((ext_vector_type(4))) unsigned uint4v;

__device__ __forceinline__ unsigned short f2bf(float f) {      // RNE fp32->bf16
  unsigned u = __float_as_uint(f);
  u = u + 0x7FFFu + ((u >> 16) & 1u);
  return (unsigned short)(u >> 16);
}
__device__ __forceinline__ unsigned cvt_pk_bf16(float lo, float hi) {
  unsigned r;                                        // {hi16: bf16(hi), lo16: bf16(lo)}
  asm("v_cvt_pk_bf16_f32 %0, %1, %2" : "=v"(r) : "v"(lo), "v"(hi));
  return r;
}

// ---------------------------------------------------------------------------
// Kernel W: weights in tap-pair MFMA A-fragment order (verified R6).
// K-step = (round rho: 16 ics) x (pair j: taps 2j, 2j+1). Lane l: a=l>>4,
// half=a>>1 (tap within pair), oct=a&1 (ic octet). Tap 9 = zero pad.
// wf[T=((rho*5+j)*4+t)*64+l][e] = bf16(w[16t+(l&15)][16rho+8oct+e][2j+half])
// ---------------------------------------------------------------------------
__global__ void wfrag_kernel(const float* __restrict__ w, short* __restrict__ wf) {
  const int T = blockIdx.x * 256 + threadIdx.x;      // 5120 fragments
  if (T >= 5120) return;
  const int l    = T & 63;
  const int t    = (T >> 6) & 3;
  const int g    = T >> 8;                           // rho*5 + j
  const int j    = g % 5;
  const int rho  = g / 5;
  const int half = (l >> 5) & 1;
  const int oct  = (l >> 4) & 1;
  const int n    = 2 * j + half;
  const int oc   = t * 16 + (l & 15);
  const int ic0  = rho * 16 + oct * 8;
  short8v v;
#pragma unroll
  for (int e = 0; e < 8; ++e)
    v[e] = (n < 9) ? (short)f2bf(w[(oc * CIN + ic0 + e) * 9 + n]) : (short)0;
  *(short8v*)(wf + (size_t)T * 8) = v;
}

// ---------------------------------------------------------------------------
// Kernel A: offset conv (verified R6, unchanged). Store off[b][c][ch][r].
// ---------------------------------------------------------------------------
__global__ __launch_bounds__(256) void offs_kernel(
    const float* __restrict__ x, const float* __restrict__ pw,
    const float* __restrict__ pb, float* __restrict__ off)
{
  const int b  = blockIdx.y;
  const int mb = blockIdx.z * 6;             // 0, 6, 12
  const int bx = blockIdx.x;
  const int r = (bx >> 2) * 4 + (threadIdx.x >> 6);
  const int c = (bx & 3) * 64 + (threadIdx.x & 63);

  float acc[6];
#pragma unroll
  for (int m = 0; m < 6; ++m) acc[m] = pb[mb + m];

  const float* xb = x + (size_t)b * CIN * HW2;
  for (int ic = 0; ic < CIN; ++ic) {
    const float* xc = xb + ic * HW2;
    float v[9];
#pragma unroll
    for (int dr = 0; dr < 3; ++dr) {
      const int rr = r - 1 + dr;
#pragma unroll
      for (int dc = 0; dc < 3; ++dc) {
        const int cc = c - 1 + dc;
        const bool ok = (rr >= 0) & (rr < HW) & (cc >= 0) & (cc < HW);
        v[dr * 3 + dc] = ok ? xc[rr * HW + cc] : 0.f;
      }
    }
#pragma unroll
    for (int m = 0; m < 6; ++m) {
      const float* wp = pw + (((mb + m) * CIN) + ic) * 9;   // uniform -> s_load
      float a = acc[m];
#pragma unroll
      for (int k = 0; k < 9; ++k) a = fmaf(wp[k], v[k], a);
      acc[m] = a;
    }
  }
#pragma unroll
  for (int m = 0; m < 6; ++m)
    off[((size_t)(b * HW + c) * 18 + (mb + m)) * HW + r] = acc[m];
}

// ---------------------------------------------------------------------------
// Kernel B: bf16 LDS window, 48B/site (16 planes packed as 8 u32) ->
// ONE ds_read_b128 per corner -> unpack+f32 interp -> bf16 B-frags ->
// tap-pair MFMA. 4 rounds (rho = 16 ics) x 5 tap-pairs (j).
// Thread (i=lane&15, a=lane>>4): pixel r0+16wv+i, tap 2j+(a>>1),
// ic octet 16rho+8(a&1). Tap 9 handled by zero qg + zero wf.
// Corner math / fallback / C-store: verified R2/R6 code.
// ---------------------------------------------------------------------------
__global__ __launch_bounds__(256) void deform_kernel(
    const float* __restrict__ x, const float* __restrict__ off,
    const short* __restrict__ wf, float* __restrict__ out)
{
  __shared__ __align__(16) char sxb[NSITE * SSTR];   // 23,520 B -> 6 blocks/CU

  const int b    = blockIdx.y;
  const int bx   = blockIdx.x;                       // 4 r-tiles * 256 cols
  const int r0   = (bx & 3) * 64;
  const int c0   = bx >> 2;
  const int tid  = threadIdx.x;
  const int lane = tid & 63;
  const int i    = lane & 15;
  const int a    = (lane >> 4) & 3;
  const int oct  = a & 1;
  const int half = a >> 1;
  const int wv   = tid >> 6;
  const int r    = r0 + wv * 16 + i;                 // this thread's pixel row

  // ---- corner tables for this thread's 5 taps: n = 2*t5 + half ----------
  unsigned qip[5][2];                                // packed site idx, 4x16b
  float    qg[5][4];
  unsigned inwm = 0;
  const float* obp = off + (size_t)(b * HW + c0) * 18 * HW;
#pragma unroll
  for (int t5 = 0; t5 < 5; ++t5) {
    const int  n9  = 2 * t5 + half;
    const bool pad = (n9 >= 9);
    const int  n   = pad ? 0 : n9;
    const float ox = obp[(size_t)n * HW + r];
    const float oy = obp[(size_t)(9 + n) * HW + r];
    const float px = (float)(c0 + (n % 3)) + ox;     // transposed base: row ~ c
    const float py = (float)(r + (n / 3)) + oy;      // col ~ r
    const float fx = floorf(px);
    const float fy = floorf(py);
    int ltx = (int)fx, lty = (int)fy;
    int rbx = ltx + 1, rby = lty + 1;
    ltx = min(max(ltx, 0), HW + 1); lty = min(max(lty, 0), HW + 1);
    rbx = min(max(rbx, 0), HW + 1); rby = min(max(rby, 0), HW + 1);
    const float pxc = fminf(fmaxf(px, 0.f), (float)(HW + 1));
    const float pyc = fminf(fmaxf(py, 0.f), (float)(HW + 1));
    const float wxl = 1.f + (float)ltx - pxc;
    const float wxr = 1.f - ((float)rbx - pxc);
    const float wyl = 1.f + (float)lty - pyc;
    const float wyr = 1.f - ((float)rby - pyc);
    const int   cx[4] = { ltx, rbx, ltx, rbx };
    const int   cy[4] = { lty, rby, rby, lty };
    const float cg[4] = { wxl * wyl, wxr * wyr, wxl * wyr, wxr * wyl };
    bool inw = true;
    unsigned so[4];
#pragma unroll
    for (int k = 0; k < 4; ++k) {
      const int lx = cx[k] - c0 + 2;                 // window-local row
      const int ly = cy[k] - r0 + 2;                 // window-local col
      inw = inw && (lx >= 0) && (lx < RXN) && (ly >= 0) && (ly < CYN);
      const int lxc = min(max(lx, 0), RXN - 1);
      const int lyc = min(max(ly, 0), CYN - 1);
      so[k]     = (unsigned)(lxc * CYN + lyc);
      qg[t5][k] = pad ? 0.f : cg[k];                 // ring zeros handle border
    }
    qip[t5][0] = so[0] | (so[1] << 16);
    qip[t5][1] = so[2] | (so[3] << 16);
    inwm |= ((inw || pad) ? 1u : 0u) << t5;
  }

  // ---- staging site descriptors (sites tid and tid+256), reused 4 rounds --
  const int s1 = tid, s2 = tid + 256;
  int gi1 = 0, gi2 = 0; bool ok1, ok2;
  {
    const int rxl = s1 / CYN, cyl = s1 - rxl * CYN;
    const int rx = c0 - 2 + rxl, cyp = r0 - 2 + cyl;
    ok1 = (rx >= 1) & (rx <= HW) & (cyp >= 1) & (cyp <= HW);
    if (ok1) gi1 = (rx - 1) * HW + (cyp - 1);
  }
  {
    const int rxl = s2 / CYN, cyl = s2 - rxl * CYN;
    const int rx = c0 - 2 + rxl, cyp = r0 - 2 + cyl;
    ok2 = (s2 < NSITE) & (rx >= 1) & (rx <= HW) & (cyp >= 1) & (cyp <= HW);
    if (ok2) gi2 = (rx - 1) * HW + (cyp - 1);
  }

  f32x4 acc[4];
#pragma unroll
  for (int t = 0; t < 4; ++t) acc[t] = (f32x4){0.f, 0.f, 0.f, 0.f};

  const float* xb = x + (size_t)b * CIN * HW2;

#pragma unroll 1
  for (int rho = 0; rho < 4; ++rho) {
    // ------------- stage 16 planes as packed bf16 pairs -------------------
    const float* xsrc = xb + (size_t)(rho * 16) * HW2;
    {
      uint4v w0, w1;
#pragma unroll
      for (int m = 0; m < 4; ++m) {
        const float* xA = xsrc + (size_t)(2 * m) * HW2;
        const float* xB = xA + HW2;
        w0[m] = cvt_pk_bf16(ok1 ? xA[gi1] : 0.f, ok1 ? xB[gi1] : 0.f);
      }
#pragma unroll
      for (int m = 0; m < 4; ++m) {
        const float* xA = xsrc + (size_t)(8 + 2 * m) * HW2;
        const float* xB = xA + HW2;
        w1[m] = cvt_pk_bf16(ok1 ? xA[gi1] : 0.f, ok1 ? xB[gi1] : 0.f);
      }
      *(uint4v*)(sxb + s1 * SSTR)      = w0;
      *(uint4v*)(sxb + s1 * SSTR + 16) = w1;
      if (s2 < NSITE) {
        uint4v u0, u1;
#pragma unroll
        for (int m = 0; m < 4; ++m) {
          const float* xA = xsrc + (size_t)(2 * m) * HW2;
          const float* xB = xA + HW2;
          u0[m] = cvt_pk_bf16(ok2 ? xA[gi2] : 0.f, ok2 ? xB[gi2] : 0.f);
        }
#pragma unroll
        for (int m = 0; m < 4; ++m) {
          const float* xA = xsrc + (size_t)(8 + 2 * m) * HW2;
          const float* xB = xA + HW2;
          u1[m] = cvt_pk_bf16(ok2 ? xA[gi2] : 0.f, ok2 ? xB[gi2] : 0.f);
        }
        *(uint4v*)(sxb + s2 * SSTR)      = u0;
        *(uint4v*)(sxb + s2 * SSTR + 16) = u1;
      }
    }
    __syncthreads();

    // ------------- sample (1 b128/corner) + MFMA over 5 tap-pairs ---------
    const short* wfr = wf + ((size_t)(rho * 5 * 4) * 64 + lane) * 8;
    const char*  sbo = sxb + oct * 16;               // octet byte offset
#pragma unroll
    for (int j = 0; j < 5; ++j) {
      short8v bfr;
      if (__all((inwm >> j) & 1)) {
        const unsigned sA = qip[j][0] & 0xFFFFu, sB = qip[j][0] >> 16;
        const unsigned sC = qip[j][1] & 0xFFFFu, sD = qip[j][1] >> 16;
        const uint4v A = *(const uint4v*)(sbo + sA * SSTR);
        const uint4v B = *(const uint4v*)(sbo + sB * SSTR);
        const uint4v C = *(const uint4v*)(sbo + sC * SSTR);
        const uint4v D = *(const uint4v*)(sbo + sD * SSTR);
        const float g0 = qg[j][0], g1 = qg[j][1], g2 = qg[j][2], g3 = qg[j][3];
        uint4v bw;
#pragma unroll
        for (int m = 0; m < 4; ++m) {
          const float alo = __uint_as_float(A[m] << 16);
          const float ahi = __uint_as_float(A[m] & 0xFFFF0000u);
          const float blo = __uint_as_float(B[m] << 16);
          const float bhi = __uint_as_float(B[m] & 0xFFFF0000u);
          const float clo = __uint_as_float(C[m] << 16);
          const float chi = __uint_as_float(C[m] & 0xFFFF0000u);
          const float dlo = __uint_as_float(D[m] << 16);
          const float dhi = __uint_as_float(D[m] & 0xFFFF0000u);
          float sl = g0 * alo;
          sl = fmaf(g1, blo, sl); sl = fmaf(g2, clo, sl); sl = fmaf(g3, dlo, sl);
          float sh = g0 * ahi;
          sh = fmaf(g1, bhi, sh); sh = fmaf(g2, chi, sh); sh = fmaf(g3, dhi, sh);
          bw[m] = cvt_pk_bf16(sl, sh);
        }
        bfr = __builtin_bit_cast(short8v, bw);
      } else {
        // rare fallback: verified global fp32 gather for this thread's tap
        const int  n9  = 2 * j + half;
        const bool pad = (n9 >= 9);
        const int  n   = pad ? 0 : n9;
        const float ox = obp[(size_t)n * HW + r];
        const float oy = obp[(size_t)(9 + n) * HW + r];
        const float px = (float)(c0 + (n % 3)) + ox;
        const float py = (float)(r + (n / 3)) + oy;
        const float fx = floorf(px);
        const float fy = floorf(py);
        int ltx = (int)fx, lty = (int)fy;
        int rbx = ltx + 1, rby = lty + 1;
        ltx = min(max(ltx, 0), HW + 1); lty = min(max(lty, 0), HW + 1);
        rbx = min(max(rbx, 0), HW + 1); rby = min(max(rby, 0), HW + 1);
        const float pxc = fminf(fmaxf(px, 0.f), (float)(HW + 1));
        const float pyc = fminf(fmaxf(py, 0.f), (float)(HW + 1));
        const float wxl = 1.f + (float)ltx - pxc;
        const float wxr = 1.f - ((float)rbx - pxc);
        const float wyl = 1.f + (float)lty - pyc;
        const float wyr = 1.f - ((float)rby - pyc);
        const int   cxs[4] = { ltx, rbx, ltx, rbx };
        const int   cys[4] = { lty, rby, rby, lty };
        const float cgs[4] = { wxl * wyl, wxr * wyr, wxl * wyr, wxr * wyl };
        int gi[4]; float gw[4];
#pragma unroll
        for (int k = 0; k < 4; ++k) {
          const bool ok = (cxs[k] >= 1) & (cxs[k] <= HW) & (cys[k] >= 1) & (cys[k] <= HW);
          gi[k] = ok ? ((cxs[k] - 1) * HW + (cys[k] - 1)) : 0;
          gw[k] = (ok && !pad) ? cgs[k] : 0.f;
        }
        const float* xpl = xb + (size_t)(rho * 16 + oct * 8) * HW2;
#pragma unroll
        for (int e = 0; e < 8; ++e) {
          const float* xe = xpl + (size_t)e * HW2;
          float sv = gw[0] * xe[gi[0]];
          sv = fmaf(gw[1], xe[gi[1]], sv);
          sv = fmaf(gw[2], xe[gi[2]], sv);
          sv = fmaf(gw[3], xe[gi[3]], sv);
          bfr[e] = (short)f2bf(sv);
        }
      }
#pragma unroll
      for (int t = 0; t < 4; ++t) {
        const short8v afr = *(const short8v*)(wfr + ((size_t)(j * 4 + t)) * 64 * 8);
        acc[t] = __builtin_amdgcn_mfma_f32_16x16x32_bf16(afr, bfr, acc[t], 0, 0, 0);
      }
    }
    __syncthreads();
  }

  // C/D store (R2-verified): col = i = pixel, row(oc) = t*16 + a*4 + jj.
#pragma unroll
  for (int t = 0; t < 4; ++t)
#pragma unroll
    for (int jj = 0; jj < 4; ++jj) {
      const int oc = t * 16 + a * 4 + jj;
      out[((size_t)(b * COUT + oc)) * HW2 + (size_t)r * HW + c0] = acc[t][jj];
    }
}

// ---------------------------------------------------------------------------
extern "C" void kernel_launch(void* const* d_in, const int* in_sizes, int n_in,
                              void* d_out, int out_size, void* d_ws, size_t ws_size,
                              hipStream_t stream) {
  const float* x  = (const float*)d_in[0];   // (2,64,256,256)
  const float* pw = (const float*)d_in[1];   // (18,64,3,3)
  const float* pb = (const float*)d_in[2];   // (18,)
  const float* w  = (const float*)d_in[3];   // (64,64,3,3)
  float* out = (float*)d_out;                // (2,64,256,256)

  float* off = (float*)d_ws;                                     // 9,437,184 B
  short* wfg = (short*)((char*)d_ws + (size_t)2 * 18 * HW2 * 4); // +81,920 B

  wfrag_kernel<<<20, 256, 0, stream>>>(w, wfg);
  dim3 gridA(256, 2, 3);
  offs_kernel<<<gridA, 256, 0, stream>>>(x, pw, pb, off);
  dim3 gridB(1024, 2);
  deform_kernel<<<gridB, 256, 0, stream>>>(x, off, wfg, out);
}

// Round 9
// 206.626 us; speedup vs baseline: 3.1720x; 1.2505x over previous
//
#include <hip/hip_runtime.h>

#define HW   256
#define HW2  (HW * HW)
#define CIN  64
#define COUT 64

#define RXN   7              // deform window rows: padded row coords c0-2 .. c0+4
#define CYN   70             // deform window cols: padded col coords r0-2 .. r0+67
#define NSITE (RXN * CYN)    // 490
#define SSTR  48             // bytes/site: 16 bf16 planes (32B) + 16B pad; 16-aligned

#define ONS   198            // offs window sites: 66 rows x 3 cols
#define OSTR  144            // bytes/site: 64 bf16 planes (128B) + 16B pad; 16-aligned

typedef __attribute__((ext_vector_type(8))) short short8v;     // 8 bf16
typedef __attribute__((ext_vector_type(4))) float f32x4;
typedef __attribute__((ext_vector_type(4))) unsigned uint4v;

__device__ __forceinline__ unsigned short f2bf(float f) {      // RNE fp32->bf16
  unsigned u = __float_as_uint(f);
  u = u + 0x7FFFu + ((u >> 16) & 1u);
  return (unsigned short)(u >> 16);
}
__device__ __forceinline__ unsigned cvt_pk_bf16(float lo, float hi) {
  unsigned r;                                        // {hi16: bf16(hi), lo16: bf16(lo)}
  asm("v_cvt_pk_bf16_f32 %0, %1, %2" : "=v"(r) : "v"(lo), "v"(hi));
  return r;
}

// ---------------------------------------------------------------------------
// Kernel W (merged): T<5120 -> deform weights wf (verified R6/R7 order);
// T>=5120 -> offs weights wf2, same tap-pair order, M-tiles t in {0,1},
// zero-padded for oc>=18 and tap 9.
// ---------------------------------------------------------------------------
__global__ void wfrag_kernel(const float* __restrict__ w, const float* __restrict__ pw,
                             short* __restrict__ wf, short* __restrict__ wf2) {
  const int T = blockIdx.x * 256 + threadIdx.x;      // 5120 + 2560 fragments
  if (T < 5120) {
    const int l    = T & 63;
    const int t    = (T >> 6) & 3;
    const int g    = T >> 8;                         // rho*5 + j
    const int j    = g % 5;
    const int rho  = g / 5;
    const int half = (l >> 5) & 1;
    const int oct  = (l >> 4) & 1;
    const int n    = 2 * j + half;
    const int oc   = t * 16 + (l & 15);
    const int ic0  = rho * 16 + oct * 8;
    short8v v;
#pragma unroll
    for (int e = 0; e < 8; ++e)
      v[e] = (n < 9) ? (short)f2bf(w[(oc * CIN + ic0 + e) * 9 + n]) : (short)0;
    *(short8v*)(wf + (size_t)T * 8) = v;
  } else if (T < 7680) {
    const int T2   = T - 5120;
    const int l    = T2 & 63;
    const int t    = (T2 >> 6) & 1;
    const int g    = T2 >> 7;                        // rho*5 + j
    const int j    = g % 5;
    const int rho  = g / 5;
    const int half = (l >> 5) & 1;
    const int oct  = (l >> 4) & 1;
    const int n    = 2 * j + half;
    const int oc   = t * 16 + (l & 15);
    const int ic0  = rho * 16 + oct * 8;
    short8v v;
#pragma unroll
    for (int e = 0; e < 8; ++e)
      v[e] = (n < 9 && oc < 18) ? (short)f2bf(pw[(oc * CIN + ic0 + e) * 9 + n])
                                : (short)0;
    *(short8v*)(wf2 + (size_t)T2 * 8) = v;
  }
}

// ---------------------------------------------------------------------------
// Kernel A: offset conv via MFMA. Block = 64 pixels along r x 1 col (c0).
// Window: site (rl,kw), rl=(r-r0)+kh in 0..65, kw in 0..2; 64 bf16 planes
// pair-packed per site (144B stride). B-frag per (rho,j) = ONE ds_read_b128
// (planes rho*16+oct*8..+7 of tap 2j+half) -- no interpolation.
// A-frag from wf2; 2 M-tiles cover ch 0..17. Bias at store. Stores coalesce
// along r (off layout [b][c][ch][r], same as R4-verified).
// ---------------------------------------------------------------------------
__global__ __launch_bounds__(256) void offs_mfma_kernel(
    const float* __restrict__ x, const short* __restrict__ wf2,
    const float* __restrict__ pb, float* __restrict__ off)
{
  __shared__ __align__(16) char sow[ONS * OSTR];     // 28,512 B

  const int b    = blockIdx.y;
  const int bx   = blockIdx.x;                       // 4 r-tiles * 256 cols
  const int r0   = (bx & 3) * 64;
  const int c0   = bx >> 2;
  const int tid  = threadIdx.x;
  const int lane = tid & 63;
  const int i    = lane & 15;
  const int g4   = lane >> 4;                        // oct = g4&1, half = g4>>1
  const int oct  = g4 & 1;
  const int half = g4 >> 1;
  const int wv   = tid >> 6;
  const int r    = r0 + wv * 16 + i;

  // ---- stage 64 planes of the 66x3 window (zeros outside image) ----------
  if (tid < ONS) {
    const int rl = tid / 3, kw = tid - rl * 3;
    const int rr = r0 - 1 + rl;                      // image row
    const int cc = c0 - 1 + kw;                      // image col
    const bool ok = (rr >= 0) & (rr < HW) & (cc >= 0) & (cc < HW);
    const float* xq = x + (size_t)b * CIN * HW2
                    + (size_t)max(rr, 0) * HW + max(cc, 0);
    char* dst = sow + tid * OSTR;
#pragma unroll
    for (int m8 = 0; m8 < 8; ++m8) {
      uint4v v;
#pragma unroll
      for (int mm = 0; mm < 4; ++mm) {
        const int pl = m8 * 8 + mm * 2;
        const float v0 = ok ? xq[(size_t)pl * HW2] : 0.f;
        const float v1 = ok ? xq[(size_t)(pl + 1) * HW2] : 0.f;
        v[mm] = cvt_pk_bf16(v0, v1);
      }
      *(uint4v*)(dst + m8 * 16) = v;
    }
  }
  __syncthreads();

  f32x4 acc0 = (f32x4){0.f, 0.f, 0.f, 0.f};
  f32x4 acc1 = (f32x4){0.f, 0.f, 0.f, 0.f};

#pragma unroll
  for (int rho = 0; rho < 4; ++rho) {
#pragma unroll
    for (int j = 0; j < 5; ++j) {
      const int n  = 2 * j + half;
      const int nn = (n < 9) ? n : 0;                // tap 9: zero A-weights
      const int kh = nn / 3, kw = nn - kh * 3;
      const int site = (wv * 16 + i + kh) * 3 + kw;
      const short8v bfr = *(const short8v*)(sow + site * OSTR + rho * 32 + oct * 16);
      const short* wfb = wf2 + ((size_t)(((rho * 5 + j) * 2) * 64) + lane) * 8;
      const short8v a0 = *(const short8v*)(wfb);
      const short8v a1 = *(const short8v*)(wfb + 64 * 8);
      acc0 = __builtin_amdgcn_mfma_f32_16x16x32_bf16(a0, bfr, acc0, 0, 0, 0);
      acc1 = __builtin_amdgcn_mfma_f32_16x16x32_bf16(a1, bfr, acc1, 0, 0, 0);
    }
  }

  // store: ch = t*16 + g4*4 + jj (C/D row), pixel = r (col). ch<18 only.
  float* ob = off + (size_t)(b * HW + c0) * 18 * HW;
#pragma unroll
  for (int jj = 0; jj < 4; ++jj) {
    const int ch = g4 * 4 + jj;                      // t=0: 0..15
    ob[(size_t)ch * HW + r] = acc0[jj] + pb[ch];
  }
  if (g4 == 0) {
#pragma unroll
    for (int jj = 0; jj < 2; ++jj) {
      const int ch = 16 + jj;                        // t=1: 16,17
      ob[(size_t)ch * HW + r] = acc1[jj] + pb[ch];
    }
  }
}

// ---------------------------------------------------------------------------
// Kernel B: deform. R7 structure + 2x2-box corner compression:
// fast path requires the RAW (unclamped) corner box inside padded image AND
// window; then sites are {s, s+1, s+70, s+71} (imm LDS offsets) and weights
// are (wxl,wyl) with complements. Clamped/out-of-window taps -> exact-math
// global fallback (verified R2/R6 code). Everything else as verified R7.
// ---------------------------------------------------------------------------
__global__ __launch_bounds__(256) void deform_kernel(
    const float* __restrict__ x, const float* __restrict__ off,
    const short* __restrict__ wf, float* __restrict__ out)
{
  __shared__ __align__(16) char sxb[NSITE * SSTR];   // 23,520 B

  const int b    = blockIdx.y;
  const int bx   = blockIdx.x;                       // 4 r-tiles * 256 cols
  const int r0   = (bx & 3) * 64;
  const int c0   = bx >> 2;
  const int tid  = threadIdx.x;
  const int lane = tid & 63;
  const int i    = lane & 15;
  const int a    = (lane >> 4) & 3;
  const int oct  = a & 1;
  const int half = a >> 1;
  const int wv   = tid >> 6;
  const int r    = r0 + wv * 16 + i;                 // this thread's pixel row

  // ---- corner tables: 1 site + (wxl,wyl) per tap --------------------------
  unsigned qsite[5];
  float    qwx[5], qwy[5];
  unsigned inwm = 0;
  const float* obp = off + (size_t)(b * HW + c0) * 18 * HW;
#pragma unroll
  for (int t5 = 0; t5 < 5; ++t5) {
    const int  n9  = 2 * t5 + half;
    const bool pad = (n9 >= 9);
    const int  n   = pad ? 0 : n9;
    const float ox = obp[(size_t)n * HW + r];
    const float oy = obp[(size_t)(9 + n) * HW + r];
    const float px = (float)(c0 + (n % 3)) + ox;     // transposed base: row ~ c
    const float py = (float)(r + (n / 3)) + oy;      // col ~ r
    const float fx = floorf(px);
    const float fy = floorf(py);
    const int ltx = (int)fx, lty = (int)fy;
    // raw box unclamped in padded image?
    const bool okc = (ltx >= 0) & (lty >= 0) & (ltx + 1 <= HW + 1) & (lty + 1 <= HW + 1);
    const int lx = ltx - c0 + 2;                     // window-local row
    const int ly = lty - r0 + 2;                     // window-local col
    const bool inw = okc & (lx >= 0) & (lx <= RXN - 2) & (ly >= 0) & (ly <= CYN - 2);
    qsite[t5] = (pad || !inw) ? 0u : (unsigned)(lx * CYN + ly);
    qwx[t5]   = 1.f + fx - px;                       // wxl (exact in fast path)
    qwy[t5]   = 1.f + fy - py;                       // wyl
    inwm |= ((inw || pad) ? 1u : 0u) << t5;
  }

  // ---- staging site descriptors (sites tid and tid+256), reused 4 rounds --
  const int s1 = tid, s2 = tid + 256;
  int gi1 = 0, gi2 = 0; bool ok1, ok2;
  {
    const int rxl = s1 / CYN, cyl = s1 - rxl * CYN;
    const int rx = c0 - 2 + rxl, cyp = r0 - 2 + cyl;
    ok1 = (rx >= 1) & (rx <= HW) & (cyp >= 1) & (cyp <= HW);
    if (ok1) gi1 = (rx - 1) * HW + (cyp - 1);
  }
  {
    const int rxl = s2 / CYN, cyl = s2 - rxl * CYN;
    const int rx = c0 - 2 + rxl, cyp = r0 - 2 + cyl;
    ok2 = (s2 < NSITE) & (rx >= 1) & (rx <= HW) & (cyp >= 1) & (cyp <= HW);
    if (ok2) gi2 = (rx - 1) * HW + (cyp - 1);
  }

  f32x4 acc[4];
#pragma unroll
  for (int t = 0; t < 4; ++t) acc[t] = (f32x4){0.f, 0.f, 0.f, 0.f};

  const float* xb = x + (size_t)b * CIN * HW2;

#pragma unroll 1
  for (int rho = 0; rho < 4; ++rho) {
    // ------------- stage 16 planes as packed bf16 pairs -------------------
    const float* xsrc = xb + (size_t)(rho * 16) * HW2;
    {
      uint4v w0, w1;
#pragma unroll
      for (int m = 0; m < 4; ++m) {
        const float* xA = xsrc + (size_t)(2 * m) * HW2;
        const float* xB = xA + HW2;
        w0[m] = cvt_pk_bf16(ok1 ? xA[gi1] : 0.f, ok1 ? xB[gi1] : 0.f);
      }
#pragma unroll
      for (int m = 0; m < 4; ++m) {
        const float* xA = xsrc + (size_t)(8 + 2 * m) * HW2;
        const float* xB = xA + HW2;
        w1[m] = cvt_pk_bf16(ok1 ? xA[gi1] : 0.f, ok1 ? xB[gi1] : 0.f);
      }
      *(uint4v*)(sxb + s1 * SSTR)      = w0;
      *(uint4v*)(sxb + s1 * SSTR + 16) = w1;
      if (s2 < NSITE) {
        uint4v u0, u1;
#pragma unroll
        for (int m = 0; m < 4; ++m) {
          const float* xA = xsrc + (size_t)(2 * m) * HW2;
          const float* xB = xA + HW2;
          u0[m] = cvt_pk_bf16(ok2 ? xA[gi2] : 0.f, ok2 ? xB[gi2] : 0.f);
        }
#pragma unroll
        for (int m = 0; m < 4; ++m) {
          const float* xA = xsrc + (size_t)(8 + 2 * m) * HW2;
          const float* xB = xA + HW2;
          u1[m] = cvt_pk_bf16(ok2 ? xA[gi2] : 0.f, ok2 ? xB[gi2] : 0.f);
        }
        *(uint4v*)(sxb + s2 * SSTR)      = u0;
        *(uint4v*)(sxb + s2 * SSTR + 16) = u1;
      }
    }
    __syncthreads();

    // ------------- sample (4 b128 @ imm offsets) + MFMA -------------------
    const short* wfr = wf + ((size_t)(rho * 5 * 4) * 64 + lane) * 8;
    const char*  sbo = sxb + oct * 16;               // octet byte offset
#pragma unroll
    for (int j = 0; j < 5; ++j) {
      short8v bfr;
      if (__all((inwm >> j) & 1)) {
        const char* pbase = sbo + qsite[j] * SSTR;
        const uint4v A = *(const uint4v*)(pbase);            // (ltx, lty)
        const uint4v C = *(const uint4v*)(pbase + SSTR);     // (ltx, rby)
        const uint4v D = *(const uint4v*)(pbase + 70 * SSTR);// (rbx, lty)
        const uint4v B = *(const uint4v*)(pbase + 71 * SSTR);// (rbx, rby)
        const float wxl = qwx[j], wyl = qwy[j];
        const float wxr = 1.f - wxl, wyr = 1.f - wyl;
        const float g0 = wxl * wyl, g1 = wxr * wyr;
        const float g2 = wxl * wyr, g3 = wxr * wyl;
        uint4v bw;
#pragma unroll
        for (int m = 0; m < 4; ++m) {
          const float alo = __uint_as_float(A[m] << 16);
          const float ahi = __uint_as_float(A[m] & 0xFFFF0000u);
          const float blo = __uint_as_float(B[m] << 16);
          const float bhi = __uint_as_float(B[m] & 0xFFFF0000u);
          const float clo = __uint_as_float(C[m] << 16);
          const float chi = __uint_as_float(C[m] & 0xFFFF0000u);
          const float dlo = __uint_as_float(D[m] << 16);
          const float dhi = __uint_as_float(D[m] & 0xFFFF0000u);
          float sl = g0 * alo;
          sl = fmaf(g1, blo, sl); sl = fmaf(g2, clo, sl); sl = fmaf(g3, dlo, sl);
          float sh = g0 * ahi;
          sh = fmaf(g1, bhi, sh); sh = fmaf(g2, chi, sh); sh = fmaf(g3, dhi, sh);
          bw[m] = cvt_pk_bf16(sl, sh);
        }
        bfr = __builtin_bit_cast(short8v, bw);
      } else {
        // fallback: exact-original-math global fp32 gather for this tap
        const int  n9  = 2 * j + half;
        const bool pad = (n9 >= 9);
        const int  n   = pad ? 0 : n9;
        const float ox = obp[(size_t)n * HW + r];
        const float oy = obp[(size_t)(9 + n) * HW + r];
        const float px = (float)(c0 + (n % 3)) + ox;
        const float py = (float)(r + (n / 3)) + oy;
        const float fx = floorf(px);
        const float fy = floorf(py);
        int ltx = (int)fx, lty = (int)fy;
        int rbx = ltx + 1, rby = lty + 1;
        ltx = min(max(ltx, 0), HW + 1); lty = min(max(lty, 0), HW + 1);
        rbx = min(max(rbx, 0), HW + 1); rby = min(max(rby, 0), HW + 1);
        const float pxc = fminf(fmaxf(px, 0.f), (float)(HW + 1));
        const float pyc = fminf(fmaxf(py, 0.f), (float)(HW + 1));
        const float wxl = 1.f + (float)ltx - pxc;
        const float wxr = 1.f - ((float)rbx - pxc);
        const float wyl = 1.f + (float)lty - pyc;
        const float wyr = 1.f - ((float)rby - pyc);
        const int   cxs[4] = { ltx, rbx, ltx, rbx };
        const int   cys[4] = { lty, rby, rby, lty };
        const float cgs[4] = { wxl * wyl, wxr * wyr, wxl * wyr, wxr * wyl };
        int gi[4]; float gw[4];
#pragma unroll
        for (int k = 0; k < 4; ++k) {
          const bool ok = (cxs[k] >= 1) & (cxs[k] <= HW) & (cys[k] >= 1) & (cys[k] <= HW);
          gi[k] = ok ? ((cxs[k] - 1) * HW + (cys[k] - 1)) : 0;
          gw[k] = (ok && !pad) ? cgs[k] : 0.f;
        }
        const float* xpl = xb + (size_t)(rho * 16 + oct * 8) * HW2;
#pragma unroll
        for (int e = 0; e < 8; ++e) {
          const float* xe = xpl + (size_t)e * HW2;
          float sv = gw[0] * xe[gi[0]];
          sv = fmaf(gw[1], xe[gi[1]], sv);
          sv = fmaf(gw[2], xe[gi[2]], sv);
          sv = fmaf(gw[3], xe[gi[3]], sv);
          bfr[e] = (short)f2bf(sv);
        }
      }
#pragma unroll
      for (int t = 0; t < 4; ++t) {
        const short8v afr = *(const short8v*)(wfr + ((size_t)(j * 4 + t)) * 64 * 8);
        acc[t] = __builtin_amdgcn_mfma_f32_16x16x32_bf16(afr, bfr, acc[t], 0, 0, 0);
      }
    }
    __syncthreads();
  }

  // C/D store (R2-verified): col = i = pixel, row(oc) = t*16 + a*4 + jj.
#pragma unroll
  for (int t = 0; t < 4; ++t)
#pragma unroll
    for (int jj = 0; jj < 4; ++jj) {
      const int oc = t * 16 + a * 4 + jj;
      out[((size_t)(b * COUT + oc)) * HW2 + (size_t)r * HW + c0] = acc[t][jj];
    }
}

// ---------------------------------------------------------------------------
extern "C" void kernel_launch(void* const* d_in, const int* in_sizes, int n_in,
                              void* d_out, int out_size, void* d_ws, size_t ws_size,
                              hipStream_t stream) {
  const float* x  = (const float*)d_in[0];   // (2,64,256,256)
  const float* pw = (const float*)d_in[1];   // (18,64,3,3)
  const float* pb = (const float*)d_in[2];   // (18,)
  const float* w  = (const float*)d_in[3];   // (64,64,3,3)
  float* out = (float*)d_out;                // (2,64,256,256)

  char* wsb = (char*)d_ws;
  float* off = (float*)wsb;                                  // 9,437,184 B
  short* wfg = (short*)(wsb + (size_t)2 * 18 * HW2 * 4);     // 81,920 B
  short* wf2 = (short*)(wsb + (size_t)2 * 18 * HW2 * 4 + 81920); // 40,960 B

  wfrag_kernel<<<30, 256, 0, stream>>>(w, pw, wfg, wf2);
  dim3 grid(1024, 2);
  offs_mfma_kernel<<<grid, 256, 0, stream>>>(x, wf2, pb, off);
  deform_kernel<<<grid, 256, 0, stream>>>(x, off, wfg, out);
}